// Round 16
// baseline (272.038 us; speedup 1.0000x reference)
//
#include <hip/hip_runtime.h>
#include <hip/hip_bf16.h>
#include <cstdint>
#include <cstddef>
#include <type_traits>

typedef __attribute__((ext_vector_type(8))) short short8;
typedef __attribute__((ext_vector_type(4))) float f32x4;
typedef __attribute__((ext_vector_type(4))) unsigned short us4;

#define DEVINL __device__ __forceinline__

static constexpr int SS_ = 3;
static constexpr int HH = 56, WW = 56;
#define SCALE_Q 0.17677669529663689f   // 32^-0.5

DEVINL unsigned short f2b(float f) {
    unsigned int u = __builtin_bit_cast(unsigned int, f);
    unsigned int r = (u + 0x7FFFu + ((u >> 16) & 1u)) >> 16;
    return (unsigned short)r;
}
DEVINL float b2f(unsigned short s) {
    return __builtin_bit_cast(float, ((unsigned int)s) << 16);
}

// GELU with 3-term A&S 7.1.25 erf (|eps|<=2.5e-5 -> gelu abs err ~1e-4)
DEVINL float gelu(float v) {
    float ax = fabsf(v) * 0.70710678118654752f;
    float t = 1.0f / (1.0f + 0.47047f * ax);
    float poly = t * (0.3480242f + t * (-0.0958798f + t * 0.7478556f));
    float erfv = 1.0f - poly * __expf(-ax * ax);
    erfv = v >= 0.0f ? erfv : -erfv;
    return 0.5f * v * (1.0f + erfv);
}

// async global->LDS, 16B per lane. LDS dest must be wave-uniform base + lane*16.
DEVINL void gload_lds16(const unsigned short* g, unsigned short* l) {
    __builtin_amdgcn_global_load_lds(
        (const __attribute__((address_space(1))) unsigned int*)g,
        (__attribute__((address_space(3))) unsigned int*)l, 16, 0, 0);
}

// ---------------- fused weight convert+transpose for all 4 weights ---------
__global__ void wconv4_kernel(const float* __restrict__ w0,
                              const float* __restrict__ w1,
                              const float* __restrict__ w2,
                              const float* __restrict__ w3,
                              unsigned short* __restrict__ o0,
                              unsigned short* __restrict__ o1,
                              unsigned short* __restrict__ o2,
                              unsigned short* __restrict__ o3) {
    int b = blockIdx.x;
    const float* in; unsigned short* out; int K, N, base;
    if (b < 768)       { in = w0; out = o0; K = 256;  N = 768;  base = 0; }
    else if (b < 1024) { in = w1; out = o1; K = 256;  N = 256;  base = 768; }
    else if (b < 2048) { in = w2; out = o2; K = 256;  N = 1024; base = 1024; }
    else               { in = w3; out = o3; K = 1024; N = 256;  base = 2048; }
    int i = (b - base) * 256 + threadIdx.x;
    int k = i / N, n = i - k * N;
    out[(size_t)n * K + k] = f2b(in[i]);
}

// ---------------- LayerNorm (one wave per token), optional window gather ----
template <int MODE, typename TIN>
__global__ __launch_bounds__(256) void ln_kernel(
    const TIN* __restrict__ x, const float* __restrict__ g,
    const float* __restrict__ be, unsigned short* __restrict__ out) {
    const int wid = threadIdx.x >> 6, lane = threadIdx.x & 63;
    const int t = blockIdx.x * 4 + wid;
    int src;
    if constexpr (MODE == 1) {
        int w = t / 49, p = t - w * 49;
        int b = w >> 6, widx = w & 63;
        int wy = widx >> 3, wx = widx & 7;
        int py = p / 7, px = p - py * 7;
        int y = wy * 7 + py + SS_;  if (y >= HH) y -= HH;
        int xx = wx * 7 + px + SS_; if (xx >= WW) xx -= WW;
        src = b * (HH * WW) + y * WW + xx;
    } else {
        src = t;
    }
    float4 v;
    if constexpr (std::is_same_v<TIN, float>) {
        v = reinterpret_cast<const float4*>(x + (size_t)src * 256)[lane];
    } else {
        us4 u = reinterpret_cast<const us4*>(x + (size_t)src * 256)[lane];
        v.x = b2f(u.x); v.y = b2f(u.y); v.z = b2f(u.z); v.w = b2f(u.w);
    }
    float s = v.x + v.y + v.z + v.w;
    float q = v.x * v.x + v.y * v.y + v.z * v.z + v.w * v.w;
#pragma unroll
    for (int m = 1; m < 64; m <<= 1) {
        s += __shfl_xor(s, m);
        q += __shfl_xor(q, m);
    }
    float mean = s * (1.0f / 256.0f);
    float var = q * (1.0f / 256.0f) - mean * mean;
    float rs = rsqrtf(var + 1e-5f);
    int c = lane * 4;
    us4 o;
    o.x = f2b((v.x - mean) * rs * g[c + 0] + be[c + 0]);
    o.y = f2b((v.y - mean) * rs * g[c + 1] + be[c + 1]);
    o.z = f2b((v.z - mean) * rs * g[c + 2] + be[c + 2]);
    o.w = f2b((v.w - mean) * rs * g[c + 3] + be[c + 3]);
    *reinterpret_cast<us4*>(out + (size_t)t * 256 + c) = o;
}

// ---------------- GEMM: C[M,N] = A[M,K] @ Bt[N,K]^T + bias, epilogues -------
// R15 body with ONE change: BK 64->32 + double-buffered LDS in the SAME 32KB
// (2 x (8KB A + 8KB B)) -> occupancy unchanged, fixing R3's confound.
// Per K-step: STAGE(t+1, buf^1) issued BEFORE compute(t); __syncthreads()
// drains the stage AFTER 16 MFMAs + frag reads covered its latency (T3
// minimum-2-phase). R15 profile: QKV/FC1 at HBM 6% / Mfma 15% = latency-bound
// on the per-step vmcnt(0) drain -- this hides it under compute.
// Swizzle: 4 chunks/row -> XOR with (row&3) (4-way ds_read alias, ~1.58x on
// the small LDS-read slice; acceptable).
// EPI 0: qkv scatter (v p-major).  EPI 1: proj + window-reverse + res -> bf16.
// EPI 2: GELU -> bf16.  EPI 3: + residual(bf16) -> fp32 out.
template <int KDIM, int EPI>
__global__ __launch_bounds__(256, 4) void gemm_kernel(
    const unsigned short* __restrict__ A, const unsigned short* __restrict__ Bt,
    const float* __restrict__ bias, void* __restrict__ out0,
    const void* __restrict__ res, unsigned short* __restrict__ o_q,
    unsigned short* __restrict__ o_k, unsigned short* __restrict__ o_v) {
    constexpr int BM = 128, BN = 128, BK = 32, NK = KDIM / BK;
    __shared__ __align__(16) unsigned short As[2][BM * BK];
    __shared__ __align__(16) unsigned short Bs[2][BN * BK];
    const int tid = threadIdx.x;
    const int wid = tid >> 6, lane = tid & 63;

    // XCD-chunk swizzle (bijective: total blocks divisible by 8)
    const int nwg = gridDim.x * gridDim.y;
    const int bid = blockIdx.x + gridDim.x * blockIdx.y;
    const int nb = (bid & 7) * (nwg >> 3) + (bid >> 3);
    const int n0 = (nb % gridDim.x) * BN;
    const int m0 = (nb / gridDim.x) * BM;

    const int wm = wid >> 1, wn = wid & 1;
    const int lr = lane & 15, kg = lane >> 4;
    f32x4 acc[4][4] = {};

    // staging: BK=32 -> 4 chunks/row. flat chunk f=i*256+tid: row=f>>2,
    // slot=f&2..; global k-chunk = slot ^ (row&3); LDS dest linear f*16B.
    const int srow = tid >> 2;           // + i*64 per round
    const int sslot = tid & 3;

    auto STAGE = [&](int kt, int buf) {  // 4 gloads per thread
#pragma unroll
        for (int i = 0; i < 2; i++) {
            int row = i * 64 + srow;
            gload_lds16(A + (size_t)(m0 + row) * KDIM + kt * BK +
                            ((sslot ^ (row & 3)) << 3),
                        As[buf] + i * 2048 + tid * 8);
        }
#pragma unroll
        for (int i = 0; i < 2; i++) {
            int row = i * 64 + srow;
            gload_lds16(Bt + (size_t)(n0 + row) * KDIM + kt * BK +
                            ((sslot ^ (row & 3)) << 3),
                        Bs[buf] + i * 2048 + tid * 8);
        }
    };

    STAGE(0, 0);
    __syncthreads();
    int cur = 0;
    for (int kt = 0; kt < NK; kt++) {
        if (kt + 1 < NK) STAGE(kt + 1, cur ^ 1);   // latency hides under MFMA
        short8 a[4], b[4];
#pragma unroll
        for (int mf = 0; mf < 4; mf++) {
            int r = wm * 64 + mf * 16 + lr;
            a[mf] = *reinterpret_cast<const short8*>(
                As[cur] + r * 32 + ((kg ^ (r & 3)) << 3));
        }
#pragma unroll
        for (int nf = 0; nf < 4; nf++) {
            int r = wn * 64 + nf * 16 + lr;
            b[nf] = *reinterpret_cast<const short8*>(
                Bs[cur] + r * 32 + ((kg ^ (r & 3)) << 3));
        }
#pragma unroll
        for (int mf = 0; mf < 4; mf++)
#pragma unroll
            for (int nf = 0; nf < 4; nf++)
                acc[mf][nf] = __builtin_amdgcn_mfma_f32_16x16x32_bf16(
                    a[mf], b[nf], acc[mf][nf], 0, 0, 0);
        __syncthreads();   // stage(t+1) landed + all reads of buf[cur] done
        cur ^= 1;
    }

#pragma unroll
    for (int mf = 0; mf < 4; mf++) {
#pragma unroll
        for (int nf = 0; nf < 4; nf++) {
#pragma unroll
            for (int j = 0; j < 4; j++) {
                int row = m0 + wm * 64 + mf * 16 + kg * 4 + j;
                int col = n0 + wn * 64 + nf * 16 + lr;
                float v = acc[mf][nf][j] + bias[col];
                if constexpr (EPI == 0) {
                    int w = row / 49, p = row - w * 49;
                    int which = col >> 8, h = (col >> 5) & 7, d = col & 31;
                    size_t th = (size_t)(w * 8 + h);
                    if (which == 0)
                        o_q[th * 1568 + p * 32 + d] = f2b(v * SCALE_Q);
                    else if (which == 1)
                        o_k[th * 1568 + p * 32 + d] = f2b(v);
                    else
                        o_v[th * 1568 + p * 32 + d] = f2b(v);   // p-major, like k
                } else if constexpr (EPI == 1) {
                    int w = row / 49, p = row - w * 49;
                    int b2 = w >> 6, widx = w & 63;
                    int wy = widx >> 3, wx = widx & 7;
                    int py = p / 7, px = p - py * 7;
                    int y = wy * 7 + py + SS_;  if (y >= HH) y -= HH;
                    int xx = wx * 7 + px + SS_; if (xx >= WW) xx -= WW;
                    size_t oi = ((size_t)(b2 * 3136 + y * 56 + xx)) * 256 + col;
                    reinterpret_cast<unsigned short*>(out0)[oi] =
                        f2b(v + reinterpret_cast<const float*>(res)[oi]);
                } else if constexpr (EPI == 2) {
                    reinterpret_cast<unsigned short*>(out0)[(size_t)row * 1024 + col] =
                        f2b(gelu(v));
                } else {
                    size_t oi = (size_t)row * 256 + col;
                    reinterpret_cast<float*>(out0)[oi] =
                        v + b2f(reinterpret_cast<const unsigned short*>(res)[oi]);
                }
            }
        }
    }
}

// ---------------- fused window attention: one wave per (window, head) -------
// v arrives P-MAJOR [49][32] (same as k); staging transposes it into the
// proven d-major XOR-swizzled v_s[32][64] via 8 scalar ds_writes per chunk.
__global__ __launch_bounds__(256) void attn_kernel(
    const unsigned short* __restrict__ qg, const unsigned short* __restrict__ kgl,
    const unsigned short* __restrict__ vg, const float* __restrict__ rpt,
    unsigned short* __restrict__ out) {
    __shared__ __align__(16) unsigned short sm[4][6144];
    __shared__ unsigned short rpts[169 * 8];
    const int tid = threadIdx.x, wid = tid >> 6, lane = tid & 63;
    for (int i = tid; i < 169 * 8; i += 256) rpts[i] = f2b(rpt[i]);
    const int task = blockIdx.x * 4 + wid;
    const int w = task >> 3, h = task & 7;
    const int widx = w & 63, wy = widx >> 3, wx = widx & 7;
    unsigned short* q_s = sm[wid];
    unsigned short* k_s = sm[wid] + 2048;
    unsigned short* v_s = sm[wid] + 4096;
    unsigned short* p_s = sm[wid];
    const unsigned short* qsrc = qg + (size_t)task * 1568;
    const unsigned short* ksrc = kgl + (size_t)task * 1568;
    const unsigned short* vsrc = vg + (size_t)task * 1568;
    for (int i = lane; i < 512; i += 64) {
        int d = i >> 4, p = 48 + (i & 15);
        v_s[d * 64 + (p ^ ((d & 7) << 3))] = 0;
    }
    for (int c = lane; c < 196; c += 64) {
        int row = c >> 2, kc = c & 3;
        int off = (row * 32 + kc * 8) ^ ((row & 7) << 3);
        *reinterpret_cast<short8*>(q_s + off) =
            *reinterpret_cast<const short8*>(qsrc + c * 8);
        *reinterpret_cast<short8*>(k_s + off) =
            *reinterpret_cast<const short8*>(ksrc + c * 8);
        short8 vv = *reinterpret_cast<const short8*>(vsrc + c * 8);
        int p = c >> 2, d0 = (c & 3) * 8;
#pragma unroll
        for (int e = 0; e < 8; e++) {
            int d = d0 + e;
            v_s[d * 64 + (p ^ ((d & 7) << 3))] = (unsigned short)vv[e];
        }
    }
    __syncthreads();

    const int lr = lane & 15, kg = lane >> 4;
    short8 af[4], bf[4];
#pragma unroll
    for (int mf = 0; mf < 4; mf++) {
        int r = mf * 16 + lr;
        af[mf] = *reinterpret_cast<const short8*>(
            q_s + ((r * 32 + kg * 8) ^ ((r & 7) << 3)));
    }
#pragma unroll
    for (int nf = 0; nf < 4; nf++) {
        int r = nf * 16 + lr;
        bf[nf] = *reinterpret_cast<const short8*>(
            k_s + ((r * 32 + kg * 8) ^ ((r & 7) << 3)));
    }
    f32x4 s[4][4] = {};
#pragma unroll
    for (int mf = 0; mf < 4; mf++)
#pragma unroll
        for (int nf = 0; nf < 4; nf++)
            s[mf][nf] = __builtin_amdgcn_mfma_f32_16x16x32_bf16(af[mf], bf[nf],
                                                                s[mf][nf], 0, 0, 0);
#pragma unroll
    for (int mf = 0; mf < 4; mf++) {
#pragma unroll
        for (int j = 0; j < 4; j++) {
            int row = mf * 16 + kg * 4 + j;
            bool rvalid = row < 49;
            int qy = 0, qx = 0, gq = 0;
            if (rvalid) {
                qy = row / 7; qx = row - qy * 7;
                int yi = wy * 7 + qy, xi = wx * 7 + qx;
                gq = ((yi < 49) ? 0 : ((yi < 53) ? 1 : 2)) * 3 +
                     ((xi < 49) ? 0 : ((xi < 53) ? 1 : 2));
            }
            float L[4];
#pragma unroll
            for (int nf = 0; nf < 4; nf++) {
                int col = nf * 16 + lr;
                float val = s[mf][nf][j];
                if (rvalid && col < 49) {
                    int ky = col / 7, kx = col - ky * 7;
                    int yi = wy * 7 + ky, xi = wx * 7 + kx;
                    int gk = ((yi < 49) ? 0 : ((yi < 53) ? 1 : 2)) * 3 +
                             ((xi < 49) ? 0 : ((xi < 53) ? 1 : 2));
                    val += b2f(rpts[((qy - ky + 6) * 13 + (qx - kx + 6)) * 8 + h]);
                    if (gq != gk) val -= 100.0f;
                } else {
                    val = -1e30f;
                }
                L[nf] = val;
            }
            float m = fmaxf(fmaxf(L[0], L[1]), fmaxf(L[2], L[3]));
#pragma unroll
            for (int t2 = 1; t2 < 16; t2 <<= 1) m = fmaxf(m, __shfl_xor(m, t2));
            float P[4], psum = 0.f;
#pragma unroll
            for (int nf = 0; nf < 4; nf++) {
                P[nf] = __expf(L[nf] - m);
                psum += P[nf];
            }
#pragma unroll
            for (int t2 = 1; t2 < 16; t2 <<= 1) psum += __shfl_xor(psum, t2);
            float inv = 1.0f / psum;
#pragma unroll
            for (int nf = 0; nf < 4; nf++) {
                int col = nf * 16 + lr;
                p_s[(row * 64 + col) ^ ((row & 7) << 3)] = f2b(P[nf] * inv);
            }
        }
    }
    f32x4 o[4][2] = {};
#pragma unroll
    for (int ks = 0; ks < 2; ks++) {
        short8 pa[4], vb[2];
#pragma unroll
        for (int mf = 0; mf < 4; mf++) {
            int r = mf * 16 + lr;
            pa[mf] = *reinterpret_cast<const short8*>(
                p_s + ((r * 64 + ks * 32 + kg * 8) ^ ((r & 7) << 3)));
        }
#pragma unroll
        for (int nf = 0; nf < 2; nf++) {
            int d = nf * 16 + lr;
            vb[nf] = *reinterpret_cast<const short8*>(
                v_s + ((d * 64 + ks * 32 + kg * 8) ^ ((d & 7) << 3)));
        }
#pragma unroll
        for (int mf = 0; mf < 4; mf++)
#pragma unroll
            for (int nf = 0; nf < 2; nf++)
                o[mf][nf] = __builtin_amdgcn_mfma_f32_16x16x32_bf16(
                    pa[mf], vb[nf], o[mf][nf], 0, 0, 0);
    }
#pragma unroll
    for (int mf = 0; mf < 4; mf++) {
#pragma unroll
        for (int j = 0; j < 4; j++) {
            int row = mf * 16 + kg * 4 + j;
            if (row < 49) {
#pragma unroll
                for (int nf = 0; nf < 2; nf++) {
                    int d = nf * 16 + lr;
                    out[((size_t)w * 49 + row) * 256 + h * 32 + d] =
                        f2b(o[mf][nf][j]);
                }
            }
        }
    }
}

// ---------------- launcher --------------------------------------------------
extern "C" void kernel_launch(void* const* d_in, const int* in_sizes, int n_in,
                              void* d_out, int out_size, void* d_ws,
                              size_t ws_size, hipStream_t stream) {
    const float* x     = (const float*)d_in[0];
    const float* g1    = (const float*)d_in[1];
    const float* be1   = (const float*)d_in[2];
    const float* wqkv  = (const float*)d_in[3];
    const float* bqkv  = (const float*)d_in[4];
    const float* rpt   = (const float*)d_in[5];
    const float* wproj = (const float*)d_in[6];
    const float* bproj = (const float*)d_in[7];
    const float* g2    = (const float*)d_in[8];
    const float* be2   = (const float*)d_in[9];
    const float* wfc1  = (const float*)d_in[10];
    const float* bfc1  = (const float*)d_in[11];
    const float* wfc2  = (const float*)d_in[12];
    const float* bfc2  = (const float*)d_in[13];
    float* out = (float*)d_out;
    char* ws = (char*)d_ws;

    unsigned short* hb  = (unsigned short*)(ws);              // 25,690,112 B
    unsigned short* qg  = (unsigned short*)(ws + 25690112);   // 25,690,112
    unsigned short* kgl = (unsigned short*)(ws + 51380224);   // 25,690,112
    unsigned short* vg  = (unsigned short*)(ws + 77070336);   // 25,690,112 used
    unsigned short* x2b = (unsigned short*)(ws + 110624768);  // 25,690,112 (bf16)
    unsigned short* h2  = (unsigned short*)(ws + 162004992);  // 25,690,112
    unsigned short* wT  = (unsigned short*)(ws + 187695104);  // 1,572,864
    unsigned short* wqkvT = wT;
    unsigned short* wprojT = wT + 196608;
    unsigned short* wfc1T  = wT + 262144;
    unsigned short* wfc2T  = wT + 524288;
    unsigned short* a1 = (unsigned short*)ws;  // aliases dead hb/q/k/v

    wconv4_kernel<<<3072, 256, 0, stream>>>(wqkv, wproj, wfc1, wfc2,
                                            wqkvT, wprojT, wfc1T, wfc2T);

    ln_kernel<1, float><<<12544, 256, 0, stream>>>(x, g1, be1, hb);
    gemm_kernel<256, 0><<<dim3(6, 392), 256, 0, stream>>>(
        hb, wqkvT, bqkv, nullptr, nullptr, qg, kgl, vg);
    attn_kernel<<<2048, 256, 0, stream>>>(qg, kgl, vg, rpt, hb);
    gemm_kernel<256, 1><<<dim3(2, 392), 256, 0, stream>>>(
        hb, wprojT, bproj, x2b, x, nullptr, nullptr, nullptr);
    ln_kernel<0, unsigned short><<<12544, 256, 0, stream>>>(x2b, g2, be2, h2);
    gemm_kernel<256, 2><<<dim3(8, 392), 256, 0, stream>>>(
        h2, wfc1T, bfc1, a1, nullptr, nullptr, nullptr, nullptr);
    gemm_kernel<1024, 3><<<dim3(2, 392), 256, 0, stream>>>(
        a1, wfc2T, bfc2, out, x2b, nullptr, nullptr, nullptr);
}

// Round 17
// 257.254 us; speedup vs baseline: 1.0575x; 1.0575x over previous
//
#include <hip/hip_runtime.h>
#include <hip/hip_bf16.h>
#include <cstdint>
#include <cstddef>
#include <type_traits>

typedef __attribute__((ext_vector_type(8))) short short8;
typedef __attribute__((ext_vector_type(4))) float f32x4;
typedef __attribute__((ext_vector_type(4))) unsigned short us4;

#define DEVINL __device__ __forceinline__

static constexpr int SS_ = 3;
static constexpr int HH = 56, WW = 56;
#define SCALE_Q 0.17677669529663689f   // 32^-0.5

DEVINL unsigned short f2b(float f) {
    unsigned int u = __builtin_bit_cast(unsigned int, f);
    unsigned int r = (u + 0x7FFFu + ((u >> 16) & 1u)) >> 16;
    return (unsigned short)r;
}
DEVINL float b2f(unsigned short s) {
    return __builtin_bit_cast(float, ((unsigned int)s) << 16);
}

// GELU with 3-term A&S 7.1.25 erf (|eps|<=2.5e-5 -> gelu abs err ~1e-4)
DEVINL float gelu(float v) {
    float ax = fabsf(v) * 0.70710678118654752f;
    float t = 1.0f / (1.0f + 0.47047f * ax);
    float poly = t * (0.3480242f + t * (-0.0958798f + t * 0.7478556f));
    float erfv = 1.0f - poly * __expf(-ax * ax);
    erfv = v >= 0.0f ? erfv : -erfv;
    return 0.5f * v * (1.0f + erfv);
}

// async global->LDS, 16B per lane. LDS dest must be wave-uniform base + lane*16.
DEVINL void gload_lds16(const unsigned short* g, unsigned short* l) {
    __builtin_amdgcn_global_load_lds(
        (const __attribute__((address_space(1))) unsigned int*)g,
        (__attribute__((address_space(3))) unsigned int*)l, 16, 0, 0);
}

// ---------------- fused weight convert+transpose for all 4 weights ---------
__global__ void wconv4_kernel(const float* __restrict__ w0,
                              const float* __restrict__ w1,
                              const float* __restrict__ w2,
                              const float* __restrict__ w3,
                              unsigned short* __restrict__ o0,
                              unsigned short* __restrict__ o1,
                              unsigned short* __restrict__ o2,
                              unsigned short* __restrict__ o3) {
    int b = blockIdx.x;
    const float* in; unsigned short* out; int K, N, base;
    if (b < 768)       { in = w0; out = o0; K = 256;  N = 768;  base = 0; }
    else if (b < 1024) { in = w1; out = o1; K = 256;  N = 256;  base = 768; }
    else if (b < 2048) { in = w2; out = o2; K = 256;  N = 1024; base = 1024; }
    else               { in = w3; out = o3; K = 1024; N = 256;  base = 2048; }
    int i = (b - base) * 256 + threadIdx.x;
    int k = i / N, n = i - k * N;
    out[(size_t)n * K + k] = f2b(in[i]);
}

// ---------------- LayerNorm (one wave per token), optional window gather ----
template <int MODE, typename TIN>
__global__ __launch_bounds__(256) void ln_kernel(
    const TIN* __restrict__ x, const float* __restrict__ g,
    const float* __restrict__ be, unsigned short* __restrict__ out) {
    const int wid = threadIdx.x >> 6, lane = threadIdx.x & 63;
    const int t = blockIdx.x * 4 + wid;
    int src;
    if constexpr (MODE == 1) {
        int w = t / 49, p = t - w * 49;
        int b = w >> 6, widx = w & 63;
        int wy = widx >> 3, wx = widx & 7;
        int py = p / 7, px = p - py * 7;
        int y = wy * 7 + py + SS_;  if (y >= HH) y -= HH;
        int xx = wx * 7 + px + SS_; if (xx >= WW) xx -= WW;
        src = b * (HH * WW) + y * WW + xx;
    } else {
        src = t;
    }
    float4 v;
    if constexpr (std::is_same_v<TIN, float>) {
        v = reinterpret_cast<const float4*>(x + (size_t)src * 256)[lane];
    } else {
        us4 u = reinterpret_cast<const us4*>(x + (size_t)src * 256)[lane];
        v.x = b2f(u.x); v.y = b2f(u.y); v.z = b2f(u.z); v.w = b2f(u.w);
    }
    float s = v.x + v.y + v.z + v.w;
    float q = v.x * v.x + v.y * v.y + v.z * v.z + v.w * v.w;
#pragma unroll
    for (int m = 1; m < 64; m <<= 1) {
        s += __shfl_xor(s, m);
        q += __shfl_xor(q, m);
    }
    float mean = s * (1.0f / 256.0f);
    float var = q * (1.0f / 256.0f) - mean * mean;
    float rs = rsqrtf(var + 1e-5f);
    int c = lane * 4;
    us4 o;
    o.x = f2b((v.x - mean) * rs * g[c + 0] + be[c + 0]);
    o.y = f2b((v.y - mean) * rs * g[c + 1] + be[c + 1]);
    o.z = f2b((v.z - mean) * rs * g[c + 2] + be[c + 2]);
    o.w = f2b((v.w - mean) * rs * g[c + 3] + be[c + 3]);
    *reinterpret_cast<us4*>(out + (size_t)t * 256 + c) = o;
}

// ---------------- GEMM: C[M,N] = A[M,K] @ Bt[N,K]^T + bias, epilogues -------
// R15 body (proven 257us best): 128x128 tile, BK=64, 4 waves (2x2), 256
// threads, single-buffered 32KB LDS, __launch_bounds__(256,4), bijective
// XCD-chunk swizzle, pre-swizzled global_load_lds, swizzled ds_read_b128,
// scalar epilogues. Schedule restructures (dbuf/counted-vmcnt/B-panel) all
// regressed across R3/R5/R6/R11/R16 -- 2-barrier single-buffer is this
// tile's local optimum at K=256 in plain HIP.
// EPI 0: qkv scatter (v p-major -- R13 write-amp fix).
// EPI 1: proj + window-reverse + residual(fp32) -> bf16.
// EPI 2: GELU -> bf16.  EPI 3: + residual(bf16) -> fp32 out.
template <int KDIM, int EPI>
__global__ __launch_bounds__(256, 4) void gemm_kernel(
    const unsigned short* __restrict__ A, const unsigned short* __restrict__ Bt,
    const float* __restrict__ bias, void* __restrict__ out0,
    const void* __restrict__ res, unsigned short* __restrict__ o_q,
    unsigned short* __restrict__ o_k, unsigned short* __restrict__ o_v) {
    constexpr int BM = 128, BN = 128, BK = 64;
    __shared__ __align__(16) unsigned short As[BM * BK];
    __shared__ __align__(16) unsigned short Bs[BN * BK];
    const int tid = threadIdx.x;
    const int wid = tid >> 6, lane = tid & 63;

    // XCD-chunk swizzle (bijective: total blocks divisible by 8)
    const int nwg = gridDim.x * gridDim.y;
    const int bid = blockIdx.x + gridDim.x * blockIdx.y;
    const int nb = (bid & 7) * (nwg >> 3) + (bid >> 3);
    const int n0 = (nb % gridDim.x) * BN;
    const int m0 = (nb / gridDim.x) * BM;

    const int wm = wid >> 1, wn = wid & 1;
    const int lr = lane & 15, kg = lane >> 4;
    f32x4 acc[4][4] = {};

    // staging geometry: round i, thread tid handles flat chunk f = i*256+tid
    // row = f>>3, stored chunk pos = tid&7; global chunk = pos ^ (row&7)
    const int srow = tid >> 3;
    const int spos = tid & 7;

    for (int kt = 0; kt < KDIM; kt += BK) {
#pragma unroll
        for (int i = 0; i < 4; i++) {
            int row = i * 32 + srow;
            gload_lds16(A + (size_t)(m0 + row) * KDIM + kt + ((spos ^ (row & 7)) << 3),
                        As + i * 2048 + tid * 8);
        }
#pragma unroll
        for (int i = 0; i < 4; i++) {
            int row = i * 32 + srow;
            gload_lds16(Bt + (size_t)(n0 + row) * KDIM + kt + ((spos ^ (row & 7)) << 3),
                        Bs + i * 2048 + tid * 8);
        }
        __syncthreads();
#pragma unroll
        for (int ks = 0; ks < 2; ks++) {
            short8 a[4], b[4];
#pragma unroll
            for (int mf = 0; mf < 4; mf++) {
                int r = wm * 64 + mf * 16 + lr;
                a[mf] = *reinterpret_cast<const short8*>(
                    As + r * 64 + (((ks * 4 + kg) ^ (r & 7)) << 3));
            }
#pragma unroll
            for (int nf = 0; nf < 4; nf++) {
                int r = wn * 64 + nf * 16 + lr;
                b[nf] = *reinterpret_cast<const short8*>(
                    Bs + r * 64 + (((ks * 4 + kg) ^ (r & 7)) << 3));
            }
#pragma unroll
            for (int mf = 0; mf < 4; mf++)
#pragma unroll
                for (int nf = 0; nf < 4; nf++)
                    acc[mf][nf] = __builtin_amdgcn_mfma_f32_16x16x32_bf16(
                        a[mf], b[nf], acc[mf][nf], 0, 0, 0);
        }
        __syncthreads();
    }

#pragma unroll
    for (int mf = 0; mf < 4; mf++) {
#pragma unroll
        for (int nf = 0; nf < 4; nf++) {
#pragma unroll
            for (int j = 0; j < 4; j++) {
                int row = m0 + wm * 64 + mf * 16 + kg * 4 + j;
                int col = n0 + wn * 64 + nf * 16 + lr;
                float v = acc[mf][nf][j] + bias[col];
                if constexpr (EPI == 0) {
                    int w = row / 49, p = row - w * 49;
                    int which = col >> 8, h = (col >> 5) & 7, d = col & 31;
                    size_t th = (size_t)(w * 8 + h);
                    if (which == 0)
                        o_q[th * 1568 + p * 32 + d] = f2b(v * SCALE_Q);
                    else if (which == 1)
                        o_k[th * 1568 + p * 32 + d] = f2b(v);
                    else
                        o_v[th * 1568 + p * 32 + d] = f2b(v);   // p-major, like k
                } else if constexpr (EPI == 1) {
                    int w = row / 49, p = row - w * 49;
                    int b2 = w >> 6, widx = w & 63;
                    int wy = widx >> 3, wx = widx & 7;
                    int py = p / 7, px = p - py * 7;
                    int y = wy * 7 + py + SS_;  if (y >= HH) y -= HH;
                    int xx = wx * 7 + px + SS_; if (xx >= WW) xx -= WW;
                    size_t oi = ((size_t)(b2 * 3136 + y * 56 + xx)) * 256 + col;
                    reinterpret_cast<unsigned short*>(out0)[oi] =
                        f2b(v + reinterpret_cast<const float*>(res)[oi]);
                } else if constexpr (EPI == 2) {
                    reinterpret_cast<unsigned short*>(out0)[(size_t)row * 1024 + col] =
                        f2b(gelu(v));
                } else {
                    size_t oi = (size_t)row * 256 + col;
                    reinterpret_cast<float*>(out0)[oi] =
                        v + b2f(reinterpret_cast<const unsigned short*>(res)[oi]);
                }
            }
        }
    }
}

// ---------------- fused window attention: one wave per (window, head) -------
// v arrives P-MAJOR [49][32] (same as k); staging transposes it into the
// proven d-major XOR-swizzled v_s[32][64] via 8 scalar ds_writes per chunk.
__global__ __launch_bounds__(256) void attn_kernel(
    const unsigned short* __restrict__ qg, const unsigned short* __restrict__ kgl,
    const unsigned short* __restrict__ vg, const float* __restrict__ rpt,
    unsigned short* __restrict__ out) {
    __shared__ __align__(16) unsigned short sm[4][6144];
    __shared__ unsigned short rpts[169 * 8];
    const int tid = threadIdx.x, wid = tid >> 6, lane = tid & 63;
    for (int i = tid; i < 169 * 8; i += 256) rpts[i] = f2b(rpt[i]);
    const int task = blockIdx.x * 4 + wid;
    const int w = task >> 3, h = task & 7;
    const int widx = w & 63, wy = widx >> 3, wx = widx & 7;
    unsigned short* q_s = sm[wid];
    unsigned short* k_s = sm[wid] + 2048;
    unsigned short* v_s = sm[wid] + 4096;
    unsigned short* p_s = sm[wid];
    const unsigned short* qsrc = qg + (size_t)task * 1568;
    const unsigned short* ksrc = kgl + (size_t)task * 1568;
    const unsigned short* vsrc = vg + (size_t)task * 1568;
    for (int i = lane; i < 512; i += 64) {
        int d = i >> 4, p = 48 + (i & 15);
        v_s[d * 64 + (p ^ ((d & 7) << 3))] = 0;
    }
    for (int c = lane; c < 196; c += 64) {
        int row = c >> 2, kc = c & 3;
        int off = (row * 32 + kc * 8) ^ ((row & 7) << 3);
        *reinterpret_cast<short8*>(q_s + off) =
            *reinterpret_cast<const short8*>(qsrc + c * 8);
        *reinterpret_cast<short8*>(k_s + off) =
            *reinterpret_cast<const short8*>(ksrc + c * 8);
        short8 vv = *reinterpret_cast<const short8*>(vsrc + c * 8);
        int p = c >> 2, d0 = (c & 3) * 8;
#pragma unroll
        for (int e = 0; e < 8; e++) {
            int d = d0 + e;
            v_s[d * 64 + (p ^ ((d & 7) << 3))] = (unsigned short)vv[e];
        }
    }
    __syncthreads();

    const int lr = lane & 15, kg = lane >> 4;
    short8 af[4], bf[4];
#pragma unroll
    for (int mf = 0; mf < 4; mf++) {
        int r = mf * 16 + lr;
        af[mf] = *reinterpret_cast<const short8*>(
            q_s + ((r * 32 + kg * 8) ^ ((r & 7) << 3)));
    }
#pragma unroll
    for (int nf = 0; nf < 4; nf++) {
        int r = nf * 16 + lr;
        bf[nf] = *reinterpret_cast<const short8*>(
            k_s + ((r * 32 + kg * 8) ^ ((r & 7) << 3)));
    }
    f32x4 s[4][4] = {};
#pragma unroll
    for (int mf = 0; mf < 4; mf++)
#pragma unroll
        for (int nf = 0; nf < 4; nf++)
            s[mf][nf] = __builtin_amdgcn_mfma_f32_16x16x32_bf16(af[mf], bf[nf],
                                                                s[mf][nf], 0, 0, 0);
#pragma unroll
    for (int mf = 0; mf < 4; mf++) {
#pragma unroll
        for (int j = 0; j < 4; j++) {
            int row = mf * 16 + kg * 4 + j;
            bool rvalid = row < 49;
            int qy = 0, qx = 0, gq = 0;
            if (rvalid) {
                qy = row / 7; qx = row - qy * 7;
                int yi = wy * 7 + qy, xi = wx * 7 + qx;
                gq = ((yi < 49) ? 0 : ((yi < 53) ? 1 : 2)) * 3 +
                     ((xi < 49) ? 0 : ((xi < 53) ? 1 : 2));
            }
            float L[4];
#pragma unroll
            for (int nf = 0; nf < 4; nf++) {
                int col = nf * 16 + lr;
                float val = s[mf][nf][j];
                if (rvalid && col < 49) {
                    int ky = col / 7, kx = col - ky * 7;
                    int yi = wy * 7 + ky, xi = wx * 7 + kx;
                    int gk = ((yi < 49) ? 0 : ((yi < 53) ? 1 : 2)) * 3 +
                             ((xi < 49) ? 0 : ((xi < 53) ? 1 : 2));
                    val += b2f(rpts[((qy - ky + 6) * 13 + (qx - kx + 6)) * 8 + h]);
                    if (gq != gk) val -= 100.0f;
                } else {
                    val = -1e30f;
                }
                L[nf] = val;
            }
            float m = fmaxf(fmaxf(L[0], L[1]), fmaxf(L[2], L[3]));
#pragma unroll
            for (int t2 = 1; t2 < 16; t2 <<= 1) m = fmaxf(m, __shfl_xor(m, t2));
            float P[4], psum = 0.f;
#pragma unroll
            for (int nf = 0; nf < 4; nf++) {
                P[nf] = __expf(L[nf] - m);
                psum += P[nf];
            }
#pragma unroll
            for (int t2 = 1; t2 < 16; t2 <<= 1) psum += __shfl_xor(psum, t2);
            float inv = 1.0f / psum;
#pragma unroll
            for (int nf = 0; nf < 4; nf++) {
                int col = nf * 16 + lr;
                p_s[(row * 64 + col) ^ ((row & 7) << 3)] = f2b(P[nf] * inv);
            }
        }
    }
    f32x4 o[4][2] = {};
#pragma unroll
    for (int ks = 0; ks < 2; ks++) {
        short8 pa[4], vb[2];
#pragma unroll
        for (int mf = 0; mf < 4; mf++) {
            int r = mf * 16 + lr;
            pa[mf] = *reinterpret_cast<const short8*>(
                p_s + ((r * 64 + ks * 32 + kg * 8) ^ ((r & 7) << 3)));
        }
#pragma unroll
        for (int nf = 0; nf < 2; nf++) {
            int d = nf * 16 + lr;
            vb[nf] = *reinterpret_cast<const short8*>(
                v_s + ((d * 64 + ks * 32 + kg * 8) ^ ((d & 7) << 3)));
        }
#pragma unroll
        for (int mf = 0; mf < 4; mf++)
#pragma unroll
            for (int nf = 0; nf < 2; nf++)
                o[mf][nf] = __builtin_amdgcn_mfma_f32_16x16x32_bf16(
                    pa[mf], vb[nf], o[mf][nf], 0, 0, 0);
    }
#pragma unroll
    for (int mf = 0; mf < 4; mf++) {
#pragma unroll
        for (int j = 0; j < 4; j++) {
            int row = mf * 16 + kg * 4 + j;
            if (row < 49) {
#pragma unroll
                for (int nf = 0; nf < 2; nf++) {
                    int d = nf * 16 + lr;
                    out[((size_t)w * 49 + row) * 256 + h * 32 + d] =
                        f2b(o[mf][nf][j]);
                }
            }
        }
    }
}

// ---------------- launcher --------------------------------------------------
extern "C" void kernel_launch(void* const* d_in, const int* in_sizes, int n_in,
                              void* d_out, int out_size, void* d_ws,
                              size_t ws_size, hipStream_t stream) {
    const float* x     = (const float*)d_in[0];
    const float* g1    = (const float*)d_in[1];
    const float* be1   = (const float*)d_in[2];
    const float* wqkv  = (const float*)d_in[3];
    const float* bqkv  = (const float*)d_in[4];
    const float* rpt   = (const float*)d_in[5];
    const float* wproj = (const float*)d_in[6];
    const float* bproj = (const float*)d_in[7];
    const float* g2    = (const float*)d_in[8];
    const float* be2   = (const float*)d_in[9];
    const float* wfc1  = (const float*)d_in[10];
    const float* bfc1  = (const float*)d_in[11];
    const float* wfc2  = (const float*)d_in[12];
    const float* bfc2  = (const float*)d_in[13];
    float* out = (float*)d_out;
    char* ws = (char*)d_ws;

    unsigned short* hb  = (unsigned short*)(ws);              // 25,690,112 B
    unsigned short* qg  = (unsigned short*)(ws + 25690112);   // 25,690,112
    unsigned short* kgl = (unsigned short*)(ws + 51380224);   // 25,690,112
    unsigned short* vg  = (unsigned short*)(ws + 77070336);   // 25,690,112 used
    unsigned short* x2b = (unsigned short*)(ws + 110624768);  // 25,690,112 (bf16)
    unsigned short* h2  = (unsigned short*)(ws + 162004992);  // 25,690,112
    unsigned short* wT  = (unsigned short*)(ws + 187695104);  // 1,572,864
    unsigned short* wqkvT = wT;
    unsigned short* wprojT = wT + 196608;
    unsigned short* wfc1T  = wT + 262144;
    unsigned short* wfc2T  = wT + 524288;
    unsigned short* a1 = (unsigned short*)ws;  // aliases dead hb/q/k/v

    wconv4_kernel<<<3072, 256, 0, stream>>>(wqkv, wproj, wfc1, wfc2,
                                            wqkvT, wprojT, wfc1T, wfc2T);

    ln_kernel<1, float><<<12544, 256, 0, stream>>>(x, g1, be1, hb);
    gemm_kernel<256, 0><<<dim3(6, 392), 256, 0, stream>>>(
        hb, wqkvT, bqkv, nullptr, nullptr, qg, kgl, vg);
    attn_kernel<<<2048, 256, 0, stream>>>(qg, kgl, vg, rpt, hb);
    gemm_kernel<256, 1><<<dim3(2, 392), 256, 0, stream>>>(
        hb, wprojT, bproj, x2b, x, nullptr, nullptr, nullptr);
    ln_kernel<0, unsigned short><<<12544, 256, 0, stream>>>(x2b, g2, be2, h2);
    gemm_kernel<256, 2><<<dim3(8, 392), 256, 0, stream>>>(
        h2, wfc1T, bfc1, a1, nullptr, nullptr, nullptr, nullptr);
    gemm_kernel<1024, 3><<<dim3(2, 392), 256, 0, stream>>>(
        a1, wfc2T, bfc2, out, x2b, nullptr, nullptr, nullptr);
}